// Round 12
// baseline (640.756 us; speedup 1.0000x reference)
//
#include <hip/hip_runtime.h>
#include <hip/hip_bf16.h>
#include <math.h>

// Problem constants
#define NROWS 100000
#define DDIM  512
#define KCL   32
#define H1DIM 512
#define H2DIM 256
#define LN2PI_2 0.9189385332046727f
#define NCHUNK 196   // ceil(100000/512)
#define NPAD  100352 // 196*512 = 784*128, zero-padded n extent for attT
#define NBLKL 784    // NPAD/128, fused gemm2_logits blocks
#define MB64  1563   // ceil(100000/64), gemm1 row-blocks

typedef __attribute__((ext_vector_type(8))) short short8;
typedef __attribute__((ext_vector_type(4))) short shortx4;
typedef __attribute__((ext_vector_type(4))) float floatx4;

// fast softplus: max(v,0) + log(1+exp(-|v|)); abs err ~1e-6, fine vs bf16 path
__device__ __forceinline__ float softplus_f(float v) {
    return fmaxf(v, 0.f) + __logf(1.f + __expf(-fabsf(v)));
}

__device__ __forceinline__ unsigned short f2bf_rne(float f) {
    unsigned int u = __float_as_uint(f);
    return (unsigned short)((u + 0x7fffu + ((u >> 16) & 1u)) >> 16);
}

__device__ __forceinline__ float bf2f(short v) {
    return __uint_as_float(((unsigned int)(unsigned short)v) << 16);
}

// 8x fp32 -> packed bf16 (RNE) via v_cvt_pk_bf16_f32 (round-3-proven)
__device__ __forceinline__ short8 cvt8(float4 a, float4 b) {
    union { unsigned int u[4]; short8 s; } r;
    asm("v_cvt_pk_bf16_f32 %0, %1, %2" : "=v"(r.u[0]) : "v"(a.x), "v"(a.y));
    asm("v_cvt_pk_bf16_f32 %0, %1, %2" : "=v"(r.u[1]) : "v"(a.z), "v"(a.w));
    asm("v_cvt_pk_bf16_f32 %0, %1, %2" : "=v"(r.u[2]) : "v"(b.x), "v"(b.y));
    asm("v_cvt_pk_bf16_f32 %0, %1, %2" : "=v"(r.u[3]) : "v"(b.z), "v"(b.w));
    return r.s;
}

// ---------------------------------------------------------------------------
// Weight transposes: W[k][n] fp32 -> BT[n][k] bf16 (x handled by gemm1_fused).
// ---------------------------------------------------------------------------
__global__ __launch_bounds__(256) void cvt_weights(
    const float* __restrict__ W1, const float* __restrict__ W2,
    const float* __restrict__ W3, short* __restrict__ W1T,
    short* __restrict__ W2T, short* __restrict__ W3T)
{
    int idx = blockIdx.x * 256 + threadIdx.x;
    const int n1 = DDIM * H1DIM;          // 262144
    const int n2 = H1DIM * H2DIM;         // 131072
    const int n3 = H2DIM * KCL;           // 8192
    if (idx < n1) {
        int n = idx % H1DIM, k = idx / H1DIM;
        W1T[(size_t)n * DDIM + k] = (short)f2bf_rne(W1[idx]);
    } else if (idx < n1 + n2) {
        int rel = idx - n1;
        int n = rel % H2DIM, k = rel / H2DIM;
        W2T[(size_t)n * H1DIM + k] = (short)f2bf_rne(W2[rel]);
    } else if (idx < n1 + n2 + n3) {
        int rel = idx - n1 - n2;
        int n = rel % KCL, k = rel / KCL;
        W3T[(size_t)n * H2DIM + k] = (short)f2bf_rne(W3[rel]);
    }
}

// ---------------------------------------------------------------------------
// Fused x-convert + GEMM1: h1 = softplus(x @ W1 + b1) bf16, xb = bf16(x)
// side-product (col-panel-0 blocks only).
// Round-12: satisfy BOTH failure axes found in rounds 8-11:
//   (a) >=2 blocks/CU (r8/r10 died at 1 blk/CU: barrier drains unhidden)
//   (b) 16 MFMA/wave/K-step (r11 died at 8: staging/barrier overhead
//       dominates; r2's proven kernel had 16)
// Config: 64x256 tile, 256 thr (4 waves), per-wave 64x64 acc[4][4];
// regs ~72+64=136 -> 12 waves/CU; LDS 51 KB -> 3 blocks/CU.
// All threads stage: A = 1 fp32 segment (cvt8), B = 4 row-segments.
// 2 col-panels: x HBM-fetched once (r10 FETCH proof), LLC absorbs re-read.
// Bit-identical h1/xb (same per-output accumulation order).
// ---------------------------------------------------------------------------
#define LDP 40   // LDS row stride in shorts (80 B): 2-way-only bank pattern
__global__ __launch_bounds__(256) void gemm1_fused(
    const float* __restrict__ x, const short* __restrict__ W1T,
    const float* __restrict__ b1, short* __restrict__ h1,
    short* __restrict__ xb)
{
    __shared__ short As[2][64 * LDP];    // 10 KB
    __shared__ short Bs[2][256 * LDP];   // 40 KB

    const int tid = threadIdx.x;
    const int lid = tid & 63;
    const int w = tid >> 6;        // 0..3
    const int lm = lid & 15;
    const int lq = lid >> 4;
    const int wcol = w * 64;       // 0,64,128,192

    const int row0 = blockIdx.y * 64;
    const int col0 = blockIdx.x * 256;
    const bool writeXb = (blockIdx.x == 0);

    const int sr = tid >> 2;       // 0..63
    const int sc = (tid & 3) << 3; // 0,8,16,24

    int gra = row0 + sr;
    const bool aval = (gra < NROWS);
    if (gra >= NROWS) gra = NROWS - 1;
    const float* Arf = x + (size_t)gra * DDIM + sc;
    short* xbw = xb + (size_t)gra * DDIM + sc;

    const short* Br0 = W1T + (size_t)(col0 + sr) * DDIM + sc;
    const short* Br1 = W1T + (size_t)(col0 + 64 + sr) * DDIM + sc;
    const short* Br2 = W1T + (size_t)(col0 + 128 + sr) * DDIM + sc;
    const short* Br3 = W1T + (size_t)(col0 + 192 + sr) * DDIM + sc;

    floatx4 acc[4][4];
    #pragma unroll
    for (int i = 0; i < 4; i++)
        #pragma unroll
        for (int j = 0; j < 4; j++)
            acc[i][j] = (floatx4){0.f, 0.f, 0.f, 0.f};

    float4 fa0, fa1;
    short8 pb0, pb1, pb2, pb3;
    fa0 = *(const float4*)Arf;
    fa1 = *(const float4*)(Arf + 4);
    pb0 = *(const short8*)Br0;
    pb1 = *(const short8*)Br1;
    pb2 = *(const short8*)Br2;
    pb3 = *(const short8*)Br3;

    const int nk = DDIM >> 5;   // 16
    for (int kt = 0; kt < nk; kt++) {
        const int buf = kt & 1;
        {
            short8 cv = cvt8(fa0, fa1);
            *(short8*)&As[buf][sr * LDP + sc] = cv;
            if (writeXb && aval) *(short8*)&xbw[kt * 32] = cv;  // xb side
        }
        *(short8*)&Bs[buf][sr * LDP + sc]         = pb0;
        *(short8*)&Bs[buf][(64 + sr) * LDP + sc]  = pb1;
        *(short8*)&Bs[buf][(128 + sr) * LDP + sc] = pb2;
        *(short8*)&Bs[buf][(192 + sr) * LDP + sc] = pb3;
        if (kt + 1 < nk) {
            int ko = (kt + 1) << 5;
            fa0 = *(const float4*)(Arf + ko);
            fa1 = *(const float4*)(Arf + ko + 4);
            pb0 = *(const short8*)(Br0 + ko);
            pb1 = *(const short8*)(Br1 + ko);
            pb2 = *(const short8*)(Br2 + ko);
            pb3 = *(const short8*)(Br3 + ko);
        }
        __syncthreads();

        short8 a[4], b[4];
        #pragma unroll
        for (int i = 0; i < 4; i++)
            a[i] = *(const short8*)&As[buf][(i * 16 + lm) * LDP + lq * 8];
        #pragma unroll
        for (int j = 0; j < 4; j++)
            b[j] = *(const short8*)&Bs[buf][(wcol + j * 16 + lm) * LDP + lq * 8];
        #pragma unroll
        for (int i = 0; i < 4; i++)
            #pragma unroll
            for (int j = 0; j < 4; j++)
                acc[i][j] = __builtin_amdgcn_mfma_f32_16x16x32_bf16(
                    a[i], b[j], acc[i][j], 0, 0, 0);
    }

    float bb[4];
    #pragma unroll
    for (int j = 0; j < 4; j++)
        bb[j] = b1[col0 + wcol + j * 16 + lm];

    #pragma unroll
    for (int i = 0; i < 4; i++) {
        #pragma unroll
        for (int reg = 0; reg < 4; reg++) {
            int rr = row0 + i * 16 + lq * 4 + reg;
            if (rr < NROWS) {
                #pragma unroll
                for (int j = 0; j < 4; j++) {
                    int c = col0 + wcol + j * 16 + lm;
                    float v = softplus_f(acc[i][j][reg] + bb[j]);
                    h1[(size_t)rr * H1DIM + c] = (short)f2bf_rne(v);
                }
            }
        }
    }
}

// ---------------------------------------------------------------------------
// Fused GEMM2 + logits + softmax + transpose. 128 rows/block, 512 thr
// (8 waves), 784 blocks. h2 never hits global memory.
// ---------------------------------------------------------------------------
__global__ __launch_bounds__(512) void gemm2_logits(
    const short* __restrict__ h1, const short* __restrict__ W2T,
    const float* __restrict__ b2, const short* __restrict__ W3T,
    const float* __restrict__ b3, short* __restrict__ attT,
    float* __restrict__ Patt)
{
    // union: staging As 2x128*LDP (10240 sh) + Bs 2x256*LDP (20480 sh)
    //        = 30720 sh; Hs [128][256] bf16 = 32768 sh aliases from 0;
    //        Ts [32][136] (4352 sh) aliases from 0 after Hs consumed.
    __shared__ __align__(16) short lds[32768];
    __shared__ float red[8][32];

    short* AsB = lds;                   // 2 x 128*LDP
    short* BsB = lds + 2 * 128 * LDP;   // 2 x 256*LDP

    const int tid = threadIdx.x;
    const int lid = tid & 63;
    const int w = tid >> 6;           // wave 0..7
    const int lm = lid & 15;
    const int lq = lid >> 4;
    const int wrow = (w & 1) * 64;
    const int wcol = (w >> 1) * 64;

    const int row0 = blockIdx.x * 128;

    const int sr = tid >> 2;          // 0..127
    const int sc = (tid & 3) << 3;    // 0,8,16,24

    int gr = row0 + sr; if (gr >= NROWS) gr = NROWS - 1;
    const short* Ar  = h1  + (size_t)gr * H1DIM + sc;
    const short* Br0 = W2T + (size_t)sr * H1DIM + sc;
    const short* Br1 = W2T + (size_t)(128 + sr) * H1DIM + sc;

    floatx4 acc[4][4];
    #pragma unroll
    for (int i = 0; i < 4; i++)
        #pragma unroll
        for (int j = 0; j < 4; j++)
            acc[i][j] = (floatx4){0.f, 0.f, 0.f, 0.f};

    short8 pa, pb0, pb1;
    pa  = *(const short8*)Ar;
    pb0 = *(const short8*)Br0;
    pb1 = *(const short8*)Br1;

    const int nk = H1DIM >> 5;   // 16
    for (int kt = 0; kt < nk; kt++) {
        const int buf = kt & 1;
        *(short8*)&AsB[buf * (128 * LDP) + sr * LDP + sc]         = pa;
        *(short8*)&BsB[buf * (256 * LDP) + sr * LDP + sc]         = pb0;
        *(short8*)&BsB[buf * (256 * LDP) + (128 + sr) * LDP + sc] = pb1;
        if (kt + 1 < nk) {
            int ko = (kt + 1) << 5;
            pa  = *(const short8*)(Ar + ko);
            pb0 = *(const short8*)(Br0 + ko);
            pb1 = *(const short8*)(Br1 + ko);
        }
        __syncthreads();

        short8 a[4], b[4];
        #pragma unroll
        for (int i = 0; i < 4; i++)
            a[i] = *(const short8*)&AsB[buf * (128 * LDP) + (wrow + i * 16 + lm) * LDP + lq * 8];
        #pragma unroll
        for (int j = 0; j < 4; j++)
            b[j] = *(const short8*)&BsB[buf * (256 * LDP) + (wcol + j * 16 + lm) * LDP + lq * 8];
        #pragma unroll
        for (int i = 0; i < 4; i++)
            #pragma unroll
            for (int j = 0; j < 4; j++)
                acc[i][j] = __builtin_amdgcn_mfma_f32_16x16x32_bf16(
                    a[i], b[j], acc[i][j], 0, 0, 0);
    }

    __syncthreads();   // all staging reads done before Hs overwrite

    // publish h2 = softplus(acc + b2) into Hs[r][c] bf16, XOR-swizzled:
    // byte = (r*512 + c*2) ^ ((r&7)<<4)
    float bb2[4];
    #pragma unroll
    for (int j = 0; j < 4; j++)
        bb2[j] = b2[wcol + j * 16 + lm];
    #pragma unroll
    for (int i = 0; i < 4; i++) {
        #pragma unroll
        for (int reg = 0; reg < 4; reg++) {
            const int r = wrow + i * 16 + lq * 4 + reg;
            const int rx = (r & 7) << 4;
            #pragma unroll
            for (int j = 0; j < 4; j++) {
                const int c = wcol + j * 16 + lm;
                float v = softplus_f(acc[i][j][reg] + bb2[j]);
                *(short*)((char*)lds + ((r * 512 + c * 2) ^ rx)) =
                    (short)f2bf_rne(v);
            }
        }
    }
    __syncthreads();

    // logits: wave w handles rows w*16 .. +15 of the tile
    short8 bf3[2][8];
    #pragma unroll
    for (int j = 0; j < 2; j++)
        #pragma unroll
        for (int s = 0; s < 8; s++)
            bf3[j][s] = *(const short8*)&W3T[(j * 16 + lm) * H2DIM + s * 32 + lq * 8];

    floatx4 lacc[2];
    lacc[0] = (floatx4){0.f, 0.f, 0.f, 0.f};
    lacc[1] = (floatx4){0.f, 0.f, 0.f, 0.f};
    const int lr = w * 16 + lm;
    const int lrx = (lr & 7) << 4;
    #pragma unroll
    for (int s = 0; s < 8; s++) {
        short8 a0 = *(const short8*)((const char*)lds +
                        ((lr * 512 + s * 64 + lq * 16) ^ lrx));
        lacc[0] = __builtin_amdgcn_mfma_f32_16x16x32_bf16(a0, bf3[0][s], lacc[0], 0, 0, 0);
        lacc[1] = __builtin_amdgcn_mfma_f32_16x16x32_bf16(a0, bf3[1][s], lacc[1], 0, 0, 0);
    }

    const float b3v0 = b3[lm];
    const float b3v1 = b3[16 + lm];
    float p0 = 0.f, p1 = 0.f;
    float e0s[4], e1s[4];
    #pragma unroll
    for (int reg = 0; reg < 4; reg++) {
        const int rg = row0 + w * 16 + lq * 4 + reg;
        float v0 = lacc[0][reg] + b3v0;
        float v1 = lacc[1][reg] + b3v1;
        float m = fmaxf(v0, v1);
        m = fmaxf(m, __shfl_xor(m, 1));
        m = fmaxf(m, __shfl_xor(m, 2));
        m = fmaxf(m, __shfl_xor(m, 4));
        m = fmaxf(m, __shfl_xor(m, 8));
        float e0 = __expf(v0 - m);
        float e1 = __expf(v1 - m);
        float sm = e0 + e1;
        sm += __shfl_xor(sm, 1);
        sm += __shfl_xor(sm, 2);
        sm += __shfl_xor(sm, 4);
        sm += __shfl_xor(sm, 8);
        float inv = 1.f / sm;
        e0 *= inv; e1 *= inv;
        if (rg >= NROWS) { e0 = 0.f; e1 = 0.f; }
        p0 += e0; p1 += e1;
        e0s[reg] = e0; e1s[reg] = e1;
    }
    p0 += __shfl_xor(p0, 16); p0 += __shfl_xor(p0, 32);
    p1 += __shfl_xor(p1, 16); p1 += __shfl_xor(p1, 32);
    if (lq == 0) { red[w][lm] = p0; red[w][16 + lm] = p1; }

    __syncthreads();   // Hs reads done -> Ts may overwrite lds

    short (*Ts)[136] = (short(*)[136])lds;   // [k][row-in-block]
    #pragma unroll
    for (int reg = 0; reg < 4; reg++) {
        const int rloc = w * 16 + lq * 4 + reg;
        Ts[lm][rloc]      = (short)f2bf_rne(e0s[reg]);
        Ts[16 + lm][rloc] = (short)f2bf_rne(e1s[reg]);
    }
    __syncthreads();

    if (tid < KCL) {
        float ps = 0.f;
        #pragma unroll
        for (int ww = 0; ww < 8; ww++) ps += red[ww][tid];
        Patt[blockIdx.x * KCL + tid] = ps;
    }

    // coalesced attT write: 32 k-rows x 128 cols bf16, 1 short8/thread
    {
        int rr = tid >> 4;             // 0..31
        int cs = (tid & 15) << 3;      // 0..120
        *(short8*)&attT[(size_t)rr * NPAD + row0 + cs] =
            *(const short8*)&Ts[rr][cs];
    }
}

// ---------------------------------------------------------------------------
// MFMA weighted moments (bf16 xb input).
// ---------------------------------------------------------------------------
__global__ __launch_bounds__(256, 4) void stats_mfma(
    const short* __restrict__ xb, const short* __restrict__ attT,
    float* __restrict__ P)
{
    __shared__ short xT[32 * 512];   // [c][r], 1024 B rows, XOR-swizzled, 32 KB

    const int tid = threadIdx.x;
    const int lane = tid & 63;
    const int lm = lane & 15;
    const int lq = lane >> 4;
    const int w = tid >> 6;
    const int kh = w >> 1;      // k-half 0..1
    const int dh = w & 1;       // d-half 0..1

    const int cblk = blockIdx.x;    // 0..195
    const int dgrp = blockIdx.y;    // 0..3
    const int n0 = cblk * 512;

    // A-fragments: attT[kh*16+lm][n0 + s*32 + lq*8 + j]
    short8 afrag[16];
    const short* arow = attT + (size_t)(kh * 16 + lm) * NPAD + n0 + lq * 8;
    #pragma unroll
    for (int s = 0; s < 16; s++)
        afrag[s] = *(const short8*)(arow + s * 32);

    const int c = tid & 31;
    const int rq = tid >> 5;                 // 0..7
    const bool full = (n0 + 512 <= NROWS);

    for (int dt = 0; dt < 4; dt++) {
        const int colf = dgrp * 128 + dt * 32 + c;
        __syncthreads();
        if (full) {
            const short* xp = xb + (size_t)n0 * DDIM + colf;
            #pragma unroll 4
            for (int p = 0; p < 16; p++) {
                int rr = p * 32 + rq * 4;
                unsigned int h0 = (unsigned short)xp[(size_t)(rr + 0) * DDIM];
                unsigned int h1 = (unsigned short)xp[(size_t)(rr + 1) * DDIM];
                unsigned int h2 = (unsigned short)xp[(size_t)(rr + 2) * DDIM];
                unsigned int h3 = (unsigned short)xp[(size_t)(rr + 3) * DDIM];
                int boff = (c << 10) + ((rr * 2) ^ ((c & 15) << 4));
                *(uint2*)((char*)xT + boff) =
                    make_uint2(h0 | (h1 << 16), h2 | (h3 << 16));
            }
        } else {
            #pragma unroll 4
            for (int p = 0; p < 16; p++) {
                int rr = p * 32 + rq * 4;
                int g0 = min(n0 + rr + 0, NROWS - 1);
                int g1 = min(n0 + rr + 1, NROWS - 1);
                int g2 = min(n0 + rr + 2, NROWS - 1);
                int g3 = min(n0 + rr + 3, NROWS - 1);
                unsigned int h0 = (unsigned short)xb[(size_t)g0 * DDIM + colf];
                unsigned int h1 = (unsigned short)xb[(size_t)g1 * DDIM + colf];
                unsigned int h2 = (unsigned short)xb[(size_t)g2 * DDIM + colf];
                unsigned int h3 = (unsigned short)xb[(size_t)g3 * DDIM + colf];
                int boff = (c << 10) + ((rr * 2) ^ ((c & 15) << 4));
                *(uint2*)((char*)xT + boff) =
                    make_uint2(h0 | (h1 << 16), h2 | (h3 << 16));
            }
        }
        __syncthreads();

        floatx4 acc1 = (floatx4){0.f, 0.f, 0.f, 0.f};
        floatx4 acc2 = (floatx4){0.f, 0.f, 0.f, 0.f};
        const int rowb = (dh * 16 + lm) << 10;
        #pragma unroll
        for (int s = 0; s < 16; s++) {
            int boff = rowb + ((s * 64 + lq * 16) ^ (lm << 4));
            short8 bx = *(const short8*)((const char*)xT + boff);
            union { short8 s8; unsigned int u[4]; } bq;
            #pragma unroll
            for (int e = 0; e < 4; e++) {
                float f0 = bf2f(bx[2 * e]);
                float f1 = bf2f(bx[2 * e + 1]);
                f0 *= f0; f1 *= f1;
                bq.u[e] = (unsigned int)f2bf_rne(f0) |
                          ((unsigned int)f2bf_rne(f1) << 16);
            }
            acc1 = __builtin_amdgcn_mfma_f32_16x16x32_bf16(
                afrag[s], bx, acc1, 0, 0, 0);
            acc2 = __builtin_amdgcn_mfma_f32_16x16x32_bf16(
                afrag[s], bq.s8, acc2, 0, 0, 0);
        }

        const size_t pbase = (size_t)cblk * 32768 +
                             (size_t)(kh * 16 + lq * 4) * 512 +
                             (size_t)(dgrp * 128 + dt * 32 + dh * 16 + lm);
        #pragma unroll
        for (int reg = 0; reg < 4; reg++) {
            P[pbase + (size_t)reg * 512]         = acc1[reg];
            P[pbase + 16384 + (size_t)reg * 512] = acc2[reg];
        }
    }
}

// ---------------------------------------------------------------------------
// Reduce partials: S12[e] = sum_c P[c][e], e in [0, 32768). 128 blocks.
// ---------------------------------------------------------------------------
__global__ __launch_bounds__(256) void stats_reduce(
    const float* __restrict__ P, const float* __restrict__ Patt,
    float* __restrict__ S12, float* __restrict__ att_sum)
{
    int e = blockIdx.x * 256 + threadIdx.x;
    float sum = 0.f;
    for (int cc = 0; cc < NCHUNK; cc++)
        sum += P[(size_t)cc * 32768 + e];
    S12[e] = sum;   // layout which*16384 + k*512 + d

    if (blockIdx.x == 0 && threadIdx.x < KCL) {
        float as = 0.f;
        for (int cc = 0; cc < NBLKL; cc++) as += Patt[cc * KCL + threadIdx.x];
        att_sum[threadIdx.x] = as;
    }
}

// ---------------------------------------------------------------------------
// Finalize stats: vars (to out), bf16 B' = [-0.5/v | m/v] per class, konst.
// ---------------------------------------------------------------------------
__global__ __launch_bounds__(256) void finalize_stats(
    const float* __restrict__ S12, const float* __restrict__ att_sum,
    short* __restrict__ Bp, float* __restrict__ konst,
    float* __restrict__ vars_out)
{
    int k = blockIdx.x;
    int tid = threadIdx.x;
    __shared__ float red[256];

    float inv_as = 1.f / att_sum[k];
    float csum = 0.f, lsum = 0.f;
    for (int d = tid; d < DDIM; d += 256) {
        float mean = S12[k * DDIM + d] * inv_as;
        float ex2  = S12[KCL * DDIM + k * DDIM + d] * inv_as;
        float var  = ex2 - mean * mean;
        vars_out[k * DDIM + d] = var;
        float iv = 1.f / var;
        Bp[(size_t)k * 1024 + d]       = (short)f2bf_rne(-0.5f * iv);
        Bp[(size_t)k * 1024 + 512 + d] = (short)f2bf_rne(mean * iv);
        csum += mean * mean * iv;
        lsum += logf(var);
    }
    red[tid] = csum;
    __syncthreads();
    for (int s = 128; s > 0; s >>= 1) {
        if (tid < s) red[tid] += red[tid + s];
        __syncthreads();
    }
    float ctot = red[0];
    __syncthreads();
    red[tid] = lsum;
    __syncthreads();
    for (int s = 128; s > 0; s >>= 1) {
        if (tid < s) red[tid] += red[tid + s];
        __syncthreads();
    }
    if (tid == 0)
        konst[k] = -0.5f * ctot - 0.5f * red[0] - DDIM * LN2PI_2;
}

// ---------------------------------------------------------------------------
// gmm_log via MFMA: out[n,k] = [x^2|x] @ Bp[k]^T + konst[k].
// 128 rows/block, register-prefetch of next dt tile.
// ---------------------------------------------------------------------------
#define LDG 40
__global__ __launch_bounds__(256) void gmm_out_mfma(
    const short* __restrict__ xb, const short* __restrict__ Bp,
    const float* __restrict__ konst, float* __restrict__ out)
{
    __shared__ short As_sq[128 * LDG];
    __shared__ short As_x[128 * LDG];

    const int tid = threadIdx.x;
    const int lane = tid & 63;
    const int lm = lane & 15;
    const int lq = lane >> 4;
    const int wid = tid >> 6;
    const int row0 = blockIdx.x * 128;

    floatx4 acc[2][2];
    #pragma unroll
    for (int i = 0; i < 2; i++)
        #pragma unroll
        for (int j = 0; j < 2; j++)
            acc[i][j] = (floatx4){0.f, 0.f, 0.f, 0.f};

    int rrh[4], segh[4], grh[4];
    bool okh[4];
    #pragma unroll
    for (int h = 0; h < 4; h++) {
        int u = tid + h * 256;         // 0..1023
        rrh[h] = u >> 3;               // 0..127
        segh[h] = (u & 7) << 2;        // 0,4,..,28
        int gr = row0 + rrh[h];
        okh[h] = (gr < NROWS);
        grh[h] = okh[h] ? gr : 0;
    }

    shortx4 pf[4];
    #pragma unroll
    for (int h = 0; h < 4; h++) {
        shortx4 v = (shortx4){0, 0, 0, 0};
        if (okh[h]) v = *(const shortx4*)&xb[(size_t)grh[h] * DDIM + segh[h]];
        pf[h] = v;
    }

    for (int dt = 0; dt < 16; dt++) {
        __syncthreads();   // prior ds_reads complete before overwrite
        #pragma unroll
        for (int h = 0; h < 4; h++) {
            shortx4 sx = pf[h];
            shortx4 sq;
            #pragma unroll
            for (int e = 0; e < 4; e++) {
                float f = bf2f(sx[e]);
                sq[e] = (short)f2bf_rne(f * f);
            }
            *(shortx4*)&As_x[rrh[h] * LDG + segh[h]]  = sx;
            *(shortx4*)&As_sq[rrh[h] * LDG + segh[h]] = sq;
        }
        if (dt + 1 < 16) {
            #pragma unroll
            for (int h = 0; h < 4; h++) {
                shortx4 v = (shortx4){0, 0, 0, 0};
                if (okh[h])
                    v = *(const shortx4*)&xb[(size_t)grh[h] * DDIM +
                                             (dt + 1) * 32 + segh[h]];
                pf[h] = v;
            }
        }
        __syncthreads();

        short8 a_sq[2], a_x[2], b_sq[2], b_x[2];
        #pragma unroll
        for (int i = 0; i < 2; i++) {
            int off = (wid * 32 + i * 16 + lm) * LDG + lq * 8;
            a_sq[i] = *(const short8*)&As_sq[off];
            a_x[i]  = *(const short8*)&As_x[off];
        }
        #pragma unroll
        for (int j = 0; j < 2; j++) {
            const size_t bo = (size_t)(j * 16 + lm) * 1024 + dt * 32 + lq * 8;
            b_sq[j] = *(const short8*)&Bp[bo];
            b_x[j]  = *(const short8*)&Bp[bo + 512];
        }
        #pragma unroll
        for (int i = 0; i < 2; i++)
            #pragma unroll
            for (int j = 0; j < 2; j++) {
                acc[i][j] = __builtin_amdgcn_mfma_f32_16x16x32_bf16(
                    a_sq[i], b_sq[j], acc[i][j], 0, 0, 0);
                acc[i][j] = __builtin_amdgcn_mfma_f32_16x16x32_bf16(
                    a_x[i], b_x[j], acc[i][j], 0, 0, 0);
            }
    }

    float kst[2];
    kst[0] = konst[lm];
    kst[1] = konst[16 + lm];

    #pragma unroll
    for (int i = 0; i < 2; i++) {
        #pragma unroll
        for (int reg = 0; reg < 4; reg++) {
            int rr = row0 + wid * 32 + i * 16 + lq * 4 + reg;
            if (rr < NROWS) {
                out[(size_t)rr * KCL + lm]      = acc[i][0][reg] + kst[0];
                out[(size_t)rr * KCL + 16 + lm] = acc[i][1][reg] + kst[1];
            }
        }
    }
}

// ---------------------------------------------------------------------------
extern "C" void kernel_launch(void* const* d_in, const int* in_sizes, int n_in,
                              void* d_out, int out_size, void* d_ws, size_t ws_size,
                              hipStream_t stream)
{
    const float* x  = (const float*)d_in[0];
    const float* W1 = (const float*)d_in[1];
    const float* b1 = (const float*)d_in[2];
    const float* W2 = (const float*)d_in[3];
    const float* b2 = (const float*)d_in[4];
    const float* W3 = (const float*)d_in[5];
    const float* b3 = (const float*)d_in[6];
    float* out = (float*)d_out;              // [N*K] gmm_log, then [K*D] vars

    // ws layout (region extents unchanged):
    short* h1b     = (short*)d_ws;                       // [N][512] bf16 (h1)
    float* h2      = (float*)(h1b + (size_t)NROWS * H1DIM); // region: xb
    float* att     = h2 + (size_t)NROWS * H2DIM;         // region: attT+Patt
    float* P       = att + (size_t)NROWS * KCL;          // 196*32768 floats
    float* PattOld = P + (size_t)NCHUNK * 32768;         // unused (layout keep)
    float* S12     = PattOld + NCHUNK * KCL;
    float* att_sum = S12 + 2 * KCL * DDIM;
    short* Bp      = (short*)(att_sum + KCL);            // [32][1024] bf16
    float* konst   = (float*)(Bp + KCL * 1024);
    (void)ws_size; (void)in_sizes; (void)n_in; (void)out_size; (void)PattOld;

    // Overlays (stream-ordered, graph-safe):
    // xb (bf16 x) lives in the h2 region, written by gemm1_fused, alive to end.
    short* xb = (short*)h2;                  // [N][512] bf16
    // attT + PattN live in the att region.
    short* attT  = (short*)att;              // [32][NPAD] bf16 (6.4 MB)
    float* PattN = (float*)(attT + (size_t)KCL * NPAD);  // [NBLKL][32]
    // Weight bf16 transposes live at the head of P (dead until stats_mfma).
    short* W1T = (short*)P;                  // [512][512]
    short* W2T = W1T + H1DIM * DDIM;         // [256][512]
    short* W3T = W2T + H2DIM * H1DIM;        // [32][256]

    cvt_weights<<<dim3(1568), 256, 0, stream>>>(W1, W2, W3, W1T, W2T, W3T);

    // h1 = softplus(x @ W1 + b1) bf16 + xb side-product.
    // 64x256 tile, 256 thr, 3 blocks/CU, 16 MFMA/wave/K-step.
    gemm1_fused<<<dim3(H1DIM / 256, MB64), 256, 0, stream>>>(
        x, W1T, b1, h1b, xb);
    // fused h2-GEMM + logits + softmax -> attT (bf16) + PattN
    gemm2_logits<<<dim3(NBLKL), 512, 0, stream>>>(
        h1b, W2T, b2, W3T, b3, attT, PattN);
    stats_mfma<<<dim3(NCHUNK, 4), 256, 0, stream>>>(xb, attT, P);
    stats_reduce<<<dim3(128), 256, 0, stream>>>(P, PattN, S12, att_sum);
    finalize_stats<<<dim3(KCL), 256, 0, stream>>>(
        S12, att_sum, Bp, konst, out + (size_t)NROWS * KCL);
    gmm_out_mfma<<<dim3((NROWS + 127) / 128), 256, 0, stream>>>(
        xb, Bp, konst, out);
}

// Round 13
// 586.510 us; speedup vs baseline: 1.0925x; 1.0925x over previous
//
#include <hip/hip_runtime.h>
#include <hip/hip_bf16.h>
#include <math.h>

// Problem constants
#define NROWS 100000
#define DDIM  512
#define KCL   32
#define H1DIM 512
#define H2DIM 256
#define LN2PI_2 0.9189385332046727f
#define NCHUNK 196   // ceil(100000/512)
#define NPAD  100352 // 196*512 = 784*128, zero-padded n extent for attT
#define NBLKL 784    // NPAD/128, fused gemm2_logits blocks

typedef __attribute__((ext_vector_type(8))) short short8;
typedef __attribute__((ext_vector_type(4))) short shortx4;
typedef __attribute__((ext_vector_type(4))) float floatx4;

// fast softplus: max(v,0) + log(1+exp(-|v|)); abs err ~1e-6, fine vs bf16 path
__device__ __forceinline__ float softplus_f(float v) {
    return fmaxf(v, 0.f) + __logf(1.f + __expf(-fabsf(v)));
}

__device__ __forceinline__ unsigned short f2bf_rne(float f) {
    unsigned int u = __float_as_uint(f);
    return (unsigned short)((u + 0x7fffu + ((u >> 16) & 1u)) >> 16);
}

__device__ __forceinline__ float bf2f(short v) {
    return __uint_as_float(((unsigned int)(unsigned short)v) << 16);
}

// 8x fp32 -> packed bf16 (RNE) via v_cvt_pk_bf16_f32 (round-3-proven)
__device__ __forceinline__ short8 cvt8(float4 a, float4 b) {
    union { unsigned int u[4]; short8 s; } r;
    asm("v_cvt_pk_bf16_f32 %0, %1, %2" : "=v"(r.u[0]) : "v"(a.x), "v"(a.y));
    asm("v_cvt_pk_bf16_f32 %0, %1, %2" : "=v"(r.u[1]) : "v"(a.z), "v"(a.w));
    asm("v_cvt_pk_bf16_f32 %0, %1, %2" : "=v"(r.u[2]) : "v"(b.x), "v"(b.y));
    asm("v_cvt_pk_bf16_f32 %0, %1, %2" : "=v"(r.u[3]) : "v"(b.z), "v"(b.w));
    return r.s;
}

// ---------------------------------------------------------------------------
// Weight transposes: W[k][n] fp32 -> BT[n][k] bf16 (x handled by gemm1_fused).
// ---------------------------------------------------------------------------
__global__ __launch_bounds__(256) void cvt_weights(
    const float* __restrict__ W1, const float* __restrict__ W2,
    const float* __restrict__ W3, short* __restrict__ W1T,
    short* __restrict__ W2T, short* __restrict__ W3T)
{
    int idx = blockIdx.x * 256 + threadIdx.x;
    const int n1 = DDIM * H1DIM;          // 262144
    const int n2 = H1DIM * H2DIM;         // 131072
    const int n3 = H2DIM * KCL;           // 8192
    if (idx < n1) {
        int n = idx % H1DIM, k = idx / H1DIM;
        W1T[(size_t)n * DDIM + k] = (short)f2bf_rne(W1[idx]);
    } else if (idx < n1 + n2) {
        int rel = idx - n1;
        int n = rel % H2DIM, k = rel / H2DIM;
        W2T[(size_t)n * H1DIM + k] = (short)f2bf_rne(W2[rel]);
    } else if (idx < n1 + n2 + n3) {
        int rel = idx - n1 - n2;
        int n = rel % KCL, k = rel / KCL;
        W3T[(size_t)n * H2DIM + k] = (short)f2bf_rne(W3[rel]);
    }
}

// ---------------------------------------------------------------------------
// Fused x-convert + GEMM1: h1 = softplus(x @ W1 + b1) bf16, and xb = bf16(x)
// written as a side product of staging.
// 128x512 tile (FULL output width -> x read ONCE, no LLC re-read), 1024 thr
// (16 waves, 2 row x 8 col of 64x64). A read fp32, converted via cvt_pk at
// LDS-store time. LDS 100 KB static.
// NOTE: this stage plateaus at ~176 us across 5 tried configurations
// (r8 176 / r9 230 / r10 190 / r11 212 / r12 223) and equals the split
// cvt+gemm path (~49+127). Reverted to the best (r8) per the pre-committed
// fallback after two consecutive failed redesigns.
// ---------------------------------------------------------------------------
#define LDP 40   // LDS row stride in shorts (80 B): 2-way-only bank pattern
__global__ __launch_bounds__(1024, 4) void gemm1_fused(
    const float* __restrict__ x, const short* __restrict__ W1T,
    const float* __restrict__ b1, short* __restrict__ h1,
    short* __restrict__ xb)
{
    __shared__ short As[2][128 * LDP];   // 20 KB
    __shared__ short Bs[2][512 * LDP];   // 80 KB

    const int tid = threadIdx.x;
    const int lid = tid & 63;
    const int w = tid >> 6;            // 0..15
    const int lm = lid & 15;
    const int lq = lid >> 4;
    const int wrow = (w & 1) * 64;
    const int wcol = (w >> 1) * 64;    // 0..448

    const int row0 = blockIdx.x * 128;

    // staging roles: sr = tid>>2, sc = (tid&3)*8
    //  B: rows sr (0..255) and 256+sr; A (tid<512 only): row sr (0..127)
    const int sr = tid >> 2;
    const int sc = (tid & 3) << 3;
    const bool doA = (tid < 512);

    const short* Br0 = W1T + (size_t)sr * DDIM + sc;
    const short* Br1 = W1T + (size_t)(256 + sr) * DDIM + sc;

    int gra = row0 + sr;               // A global row (tid<512: sr 0..127)
    if (gra >= NROWS) gra = NROWS - 1;
    const float* Arf = x + (size_t)gra * DDIM + sc;
    short* xbw = xb + (size_t)gra * DDIM + sc;

    floatx4 acc[4][4];
    #pragma unroll
    for (int i = 0; i < 4; i++)
        #pragma unroll
        for (int j = 0; j < 4; j++)
            acc[i][j] = (floatx4){0.f, 0.f, 0.f, 0.f};

    float4 fa0, fa1;
    short8 pb0, pb1;
    if (doA) {
        fa0 = *(const float4*)Arf;
        fa1 = *(const float4*)(Arf + 4);
    }
    pb0 = *(const short8*)Br0;
    pb1 = *(const short8*)Br1;

    const int nk = DDIM >> 5;   // 16
    for (int kt = 0; kt < nk; kt++) {
        const int buf = kt & 1;
        if (doA) {
            short8 cv = cvt8(fa0, fa1);
            *(short8*)&As[buf][sr * LDP + sc] = cv;
            *(short8*)&xbw[kt * 32] = cv;          // xb side-product
        }
        *(short8*)&Bs[buf][sr * LDP + sc]         = pb0;
        *(short8*)&Bs[buf][(256 + sr) * LDP + sc] = pb1;
        if (kt + 1 < nk) {
            int ko = (kt + 1) << 5;
            if (doA) {
                fa0 = *(const float4*)(Arf + ko);
                fa1 = *(const float4*)(Arf + ko + 4);
            }
            pb0 = *(const short8*)(Br0 + ko);
            pb1 = *(const short8*)(Br1 + ko);
        }
        __syncthreads();

        short8 a[4], b[4];
        #pragma unroll
        for (int i = 0; i < 4; i++)
            a[i] = *(const short8*)&As[buf][(wrow + i * 16 + lm) * LDP + lq * 8];
        #pragma unroll
        for (int j = 0; j < 4; j++)
            b[j] = *(const short8*)&Bs[buf][(wcol + j * 16 + lm) * LDP + lq * 8];
        #pragma unroll
        for (int i = 0; i < 4; i++)
            #pragma unroll
            for (int j = 0; j < 4; j++)
                acc[i][j] = __builtin_amdgcn_mfma_f32_16x16x32_bf16(
                    a[i], b[j], acc[i][j], 0, 0, 0);
    }

    float bb[4];
    #pragma unroll
    for (int j = 0; j < 4; j++)
        bb[j] = b1[wcol + j * 16 + lm];

    #pragma unroll
    for (int i = 0; i < 4; i++) {
        #pragma unroll
        for (int reg = 0; reg < 4; reg++) {
            int rr = row0 + wrow + i * 16 + lq * 4 + reg;
            if (rr < NROWS) {
                #pragma unroll
                for (int j = 0; j < 4; j++) {
                    int c = wcol + j * 16 + lm;
                    float v = softplus_f(acc[i][j][reg] + bb[j]);
                    h1[(size_t)rr * H1DIM + c] = (short)f2bf_rne(v);
                }
            }
        }
    }
}

// ---------------------------------------------------------------------------
// Fused GEMM2 + logits + softmax + transpose. 128 rows/block, 512 thr
// (8 waves), 784 blocks. h2 never hits global memory.
// ---------------------------------------------------------------------------
__global__ __launch_bounds__(512) void gemm2_logits(
    const short* __restrict__ h1, const short* __restrict__ W2T,
    const float* __restrict__ b2, const short* __restrict__ W3T,
    const float* __restrict__ b3, short* __restrict__ attT,
    float* __restrict__ Patt)
{
    // union: staging As 2x128*LDP (10240 sh) + Bs 2x256*LDP (20480 sh)
    //        = 30720 sh; Hs [128][256] bf16 = 32768 sh aliases from 0;
    //        Ts [32][136] (4352 sh) aliases from 0 after Hs consumed.
    __shared__ __align__(16) short lds[32768];
    __shared__ float red[8][32];

    short* AsB = lds;                   // 2 x 128*LDP
    short* BsB = lds + 2 * 128 * LDP;   // 2 x 256*LDP

    const int tid = threadIdx.x;
    const int lid = tid & 63;
    const int w = tid >> 6;           // wave 0..7
    const int lm = lid & 15;
    const int lq = lid >> 4;
    const int wrow = (w & 1) * 64;
    const int wcol = (w >> 1) * 64;

    const int row0 = blockIdx.x * 128;

    const int sr = tid >> 2;          // 0..127
    const int sc = (tid & 3) << 3;    // 0,8,16,24

    int gr = row0 + sr; if (gr >= NROWS) gr = NROWS - 1;
    const short* Ar  = h1  + (size_t)gr * H1DIM + sc;
    const short* Br0 = W2T + (size_t)sr * H1DIM + sc;
    const short* Br1 = W2T + (size_t)(128 + sr) * H1DIM + sc;

    floatx4 acc[4][4];
    #pragma unroll
    for (int i = 0; i < 4; i++)
        #pragma unroll
        for (int j = 0; j < 4; j++)
            acc[i][j] = (floatx4){0.f, 0.f, 0.f, 0.f};

    short8 pa, pb0, pb1;
    pa  = *(const short8*)Ar;
    pb0 = *(const short8*)Br0;
    pb1 = *(const short8*)Br1;

    const int nk = H1DIM >> 5;   // 16
    for (int kt = 0; kt < nk; kt++) {
        const int buf = kt & 1;
        *(short8*)&AsB[buf * (128 * LDP) + sr * LDP + sc]         = pa;
        *(short8*)&BsB[buf * (256 * LDP) + sr * LDP + sc]         = pb0;
        *(short8*)&BsB[buf * (256 * LDP) + (128 + sr) * LDP + sc] = pb1;
        if (kt + 1 < nk) {
            int ko = (kt + 1) << 5;
            pa  = *(const short8*)(Ar + ko);
            pb0 = *(const short8*)(Br0 + ko);
            pb1 = *(const short8*)(Br1 + ko);
        }
        __syncthreads();

        short8 a[4], b[4];
        #pragma unroll
        for (int i = 0; i < 4; i++)
            a[i] = *(const short8*)&AsB[buf * (128 * LDP) + (wrow + i * 16 + lm) * LDP + lq * 8];
        #pragma unroll
        for (int j = 0; j < 4; j++)
            b[j] = *(const short8*)&BsB[buf * (256 * LDP) + (wcol + j * 16 + lm) * LDP + lq * 8];
        #pragma unroll
        for (int i = 0; i < 4; i++)
            #pragma unroll
            for (int j = 0; j < 4; j++)
                acc[i][j] = __builtin_amdgcn_mfma_f32_16x16x32_bf16(
                    a[i], b[j], acc[i][j], 0, 0, 0);
    }

    __syncthreads();   // all staging reads done before Hs overwrite

    // publish h2 = softplus(acc + b2) into Hs[r][c] bf16, XOR-swizzled:
    // byte = (r*512 + c*2) ^ ((r&7)<<4)
    float bb2[4];
    #pragma unroll
    for (int j = 0; j < 4; j++)
        bb2[j] = b2[wcol + j * 16 + lm];
    #pragma unroll
    for (int i = 0; i < 4; i++) {
        #pragma unroll
        for (int reg = 0; reg < 4; reg++) {
            const int r = wrow + i * 16 + lq * 4 + reg;
            const int rx = (r & 7) << 4;
            #pragma unroll
            for (int j = 0; j < 4; j++) {
                const int c = wcol + j * 16 + lm;
                float v = softplus_f(acc[i][j][reg] + bb2[j]);
                *(short*)((char*)lds + ((r * 512 + c * 2) ^ rx)) =
                    (short)f2bf_rne(v);
            }
        }
    }
    __syncthreads();

    // logits: wave w handles rows w*16 .. +15 of the tile
    short8 bf3[2][8];
    #pragma unroll
    for (int j = 0; j < 2; j++)
        #pragma unroll
        for (int s = 0; s < 8; s++)
            bf3[j][s] = *(const short8*)&W3T[(j * 16 + lm) * H2DIM + s * 32 + lq * 8];

    floatx4 lacc[2];
    lacc[0] = (floatx4){0.f, 0.f, 0.f, 0.f};
    lacc[1] = (floatx4){0.f, 0.f, 0.f, 0.f};
    const int lr = w * 16 + lm;
    const int lrx = (lr & 7) << 4;
    #pragma unroll
    for (int s = 0; s < 8; s++) {
        short8 a0 = *(const short8*)((const char*)lds +
                        ((lr * 512 + s * 64 + lq * 16) ^ lrx));
        lacc[0] = __builtin_amdgcn_mfma_f32_16x16x32_bf16(a0, bf3[0][s], lacc[0], 0, 0, 0);
        lacc[1] = __builtin_amdgcn_mfma_f32_16x16x32_bf16(a0, bf3[1][s], lacc[1], 0, 0, 0);
    }

    const float b3v0 = b3[lm];
    const float b3v1 = b3[16 + lm];
    float p0 = 0.f, p1 = 0.f;
    float e0s[4], e1s[4];
    #pragma unroll
    for (int reg = 0; reg < 4; reg++) {
        const int rg = row0 + w * 16 + lq * 4 + reg;
        float v0 = lacc[0][reg] + b3v0;
        float v1 = lacc[1][reg] + b3v1;
        float m = fmaxf(v0, v1);
        m = fmaxf(m, __shfl_xor(m, 1));
        m = fmaxf(m, __shfl_xor(m, 2));
        m = fmaxf(m, __shfl_xor(m, 4));
        m = fmaxf(m, __shfl_xor(m, 8));
        float e0 = __expf(v0 - m);
        float e1 = __expf(v1 - m);
        float sm = e0 + e1;
        sm += __shfl_xor(sm, 1);
        sm += __shfl_xor(sm, 2);
        sm += __shfl_xor(sm, 4);
        sm += __shfl_xor(sm, 8);
        float inv = 1.f / sm;
        e0 *= inv; e1 *= inv;
        if (rg >= NROWS) { e0 = 0.f; e1 = 0.f; }
        p0 += e0; p1 += e1;
        e0s[reg] = e0; e1s[reg] = e1;
    }
    p0 += __shfl_xor(p0, 16); p0 += __shfl_xor(p0, 32);
    p1 += __shfl_xor(p1, 16); p1 += __shfl_xor(p1, 32);
    if (lq == 0) { red[w][lm] = p0; red[w][16 + lm] = p1; }

    __syncthreads();   // Hs reads done -> Ts may overwrite lds

    short (*Ts)[136] = (short(*)[136])lds;   // [k][row-in-block]
    #pragma unroll
    for (int reg = 0; reg < 4; reg++) {
        const int rloc = w * 16 + lq * 4 + reg;
        Ts[lm][rloc]      = (short)f2bf_rne(e0s[reg]);
        Ts[16 + lm][rloc] = (short)f2bf_rne(e1s[reg]);
    }
    __syncthreads();

    if (tid < KCL) {
        float ps = 0.f;
        #pragma unroll
        for (int ww = 0; ww < 8; ww++) ps += red[ww][tid];
        Patt[blockIdx.x * KCL + tid] = ps;
    }

    // coalesced attT write: 32 k-rows x 128 cols bf16, 1 short8/thread
    {
        int rr = tid >> 4;             // 0..31
        int cs = (tid & 15) << 3;      // 0..120
        *(short8*)&attT[(size_t)rr * NPAD + row0 + cs] =
            *(const short8*)&Ts[rr][cs];
    }
}

// ---------------------------------------------------------------------------
// MFMA weighted moments (bf16 xb input).
// ---------------------------------------------------------------------------
__global__ __launch_bounds__(256, 4) void stats_mfma(
    const short* __restrict__ xb, const short* __restrict__ attT,
    float* __restrict__ P)
{
    __shared__ short xT[32 * 512];   // [c][r], 1024 B rows, XOR-swizzled, 32 KB

    const int tid = threadIdx.x;
    const int lane = tid & 63;
    const int lm = lane & 15;
    const int lq = lane >> 4;
    const int w = tid >> 6;
    const int kh = w >> 1;      // k-half 0..1
    const int dh = w & 1;       // d-half 0..1

    const int cblk = blockIdx.x;    // 0..195
    const int dgrp = blockIdx.y;    // 0..3
    const int n0 = cblk * 512;

    // A-fragments: attT[kh*16+lm][n0 + s*32 + lq*8 + j]
    short8 afrag[16];
    const short* arow = attT + (size_t)(kh * 16 + lm) * NPAD + n0 + lq * 8;
    #pragma unroll
    for (int s = 0; s < 16; s++)
        afrag[s] = *(const short8*)(arow + s * 32);

    const int c = tid & 31;
    const int rq = tid >> 5;                 // 0..7
    const bool full = (n0 + 512 <= NROWS);

    for (int dt = 0; dt < 4; dt++) {
        const int colf = dgrp * 128 + dt * 32 + c;
        __syncthreads();
        if (full) {
            const short* xp = xb + (size_t)n0 * DDIM + colf;
            #pragma unroll 4
            for (int p = 0; p < 16; p++) {
                int rr = p * 32 + rq * 4;
                unsigned int h0 = (unsigned short)xp[(size_t)(rr + 0) * DDIM];
                unsigned int h1 = (unsigned short)xp[(size_t)(rr + 1) * DDIM];
                unsigned int h2 = (unsigned short)xp[(size_t)(rr + 2) * DDIM];
                unsigned int h3 = (unsigned short)xp[(size_t)(rr + 3) * DDIM];
                int boff = (c << 10) + ((rr * 2) ^ ((c & 15) << 4));
                *(uint2*)((char*)xT + boff) =
                    make_uint2(h0 | (h1 << 16), h2 | (h3 << 16));
            }
        } else {
            #pragma unroll 4
            for (int p = 0; p < 16; p++) {
                int rr = p * 32 + rq * 4;
                int g0 = min(n0 + rr + 0, NROWS - 1);
                int g1 = min(n0 + rr + 1, NROWS - 1);
                int g2 = min(n0 + rr + 2, NROWS - 1);
                int g3 = min(n0 + rr + 3, NROWS - 1);
                unsigned int h0 = (unsigned short)xb[(size_t)g0 * DDIM + colf];
                unsigned int h1 = (unsigned short)xb[(size_t)g1 * DDIM + colf];
                unsigned int h2 = (unsigned short)xb[(size_t)g2 * DDIM + colf];
                unsigned int h3 = (unsigned short)xb[(size_t)g3 * DDIM + colf];
                int boff = (c << 10) + ((rr * 2) ^ ((c & 15) << 4));
                *(uint2*)((char*)xT + boff) =
                    make_uint2(h0 | (h1 << 16), h2 | (h3 << 16));
            }
        }
        __syncthreads();

        floatx4 acc1 = (floatx4){0.f, 0.f, 0.f, 0.f};
        floatx4 acc2 = (floatx4){0.f, 0.f, 0.f, 0.f};
        const int rowb = (dh * 16 + lm) << 10;
        #pragma unroll
        for (int s = 0; s < 16; s++) {
            int boff = rowb + ((s * 64 + lq * 16) ^ (lm << 4));
            short8 bx = *(const short8*)((const char*)xT + boff);
            union { short8 s8; unsigned int u[4]; } bq;
            #pragma unroll
            for (int e = 0; e < 4; e++) {
                float f0 = bf2f(bx[2 * e]);
                float f1 = bf2f(bx[2 * e + 1]);
                f0 *= f0; f1 *= f1;
                bq.u[e] = (unsigned int)f2bf_rne(f0) |
                          ((unsigned int)f2bf_rne(f1) << 16);
            }
            acc1 = __builtin_amdgcn_mfma_f32_16x16x32_bf16(
                afrag[s], bx, acc1, 0, 0, 0);
            acc2 = __builtin_amdgcn_mfma_f32_16x16x32_bf16(
                afrag[s], bq.s8, acc2, 0, 0, 0);
        }

        const size_t pbase = (size_t)cblk * 32768 +
                             (size_t)(kh * 16 + lq * 4) * 512 +
                             (size_t)(dgrp * 128 + dt * 32 + dh * 16 + lm);
        #pragma unroll
        for (int reg = 0; reg < 4; reg++) {
            P[pbase + (size_t)reg * 512]         = acc1[reg];
            P[pbase + 16384 + (size_t)reg * 512] = acc2[reg];
        }
    }
}

// ---------------------------------------------------------------------------
// Reduce partials: S12[e] = sum_c P[c][e], e in [0, 32768). 128 blocks.
// ---------------------------------------------------------------------------
__global__ __launch_bounds__(256) void stats_reduce(
    const float* __restrict__ P, const float* __restrict__ Patt,
    float* __restrict__ S12, float* __restrict__ att_sum)
{
    int e = blockIdx.x * 256 + threadIdx.x;
    float sum = 0.f;
    for (int cc = 0; cc < NCHUNK; cc++)
        sum += P[(size_t)cc * 32768 + e];
    S12[e] = sum;   // layout which*16384 + k*512 + d

    if (blockIdx.x == 0 && threadIdx.x < KCL) {
        float as = 0.f;
        for (int cc = 0; cc < NBLKL; cc++) as += Patt[cc * KCL + threadIdx.x];
        att_sum[threadIdx.x] = as;
    }
}

// ---------------------------------------------------------------------------
// Finalize stats: vars (to out), bf16 B' = [-0.5/v | m/v] per class, konst.
// ---------------------------------------------------------------------------
__global__ __launch_bounds__(256) void finalize_stats(
    const float* __restrict__ S12, const float* __restrict__ att_sum,
    short* __restrict__ Bp, float* __restrict__ konst,
    float* __restrict__ vars_out)
{
    int k = blockIdx.x;
    int tid = threadIdx.x;
    __shared__ float red[256];

    float inv_as = 1.f / att_sum[k];
    float csum = 0.f, lsum = 0.f;
    for (int d = tid; d < DDIM; d += 256) {
        float mean = S12[k * DDIM + d] * inv_as;
        float ex2  = S12[KCL * DDIM + k * DDIM + d] * inv_as;
        float var  = ex2 - mean * mean;
        vars_out[k * DDIM + d] = var;
        float iv = 1.f / var;
        Bp[(size_t)k * 1024 + d]       = (short)f2bf_rne(-0.5f * iv);
        Bp[(size_t)k * 1024 + 512 + d] = (short)f2bf_rne(mean * iv);
        csum += mean * mean * iv;
        lsum += logf(var);
    }
    red[tid] = csum;
    __syncthreads();
    for (int s = 128; s > 0; s >>= 1) {
        if (tid < s) red[tid] += red[tid + s];
        __syncthreads();
    }
    float ctot = red[0];
    __syncthreads();
    red[tid] = lsum;
    __syncthreads();
    for (int s = 128; s > 0; s >>= 1) {
        if (tid < s) red[tid] += red[tid + s];
        __syncthreads();
    }
    if (tid == 0)
        konst[k] = -0.5f * ctot - 0.5f * red[0] - DDIM * LN2PI_2;
}

// ---------------------------------------------------------------------------
// gmm_log via MFMA: out[n,k] = [x^2|x] @ Bp[k]^T + konst[k].
// 128 rows/block, register-prefetch of next dt tile.
// ---------------------------------------------------------------------------
#define LDG 40
__global__ __launch_bounds__(256) void gmm_out_mfma(
    const short* __restrict__ xb, const short* __restrict__ Bp,
    const float* __restrict__ konst, float* __restrict__ out)
{
    __shared__ short As_sq[128 * LDG];
    __shared__ short As_x[128 * LDG];

    const int tid = threadIdx.x;
    const int lane = tid & 63;
    const int lm = lane & 15;
    const int lq = lane >> 4;
    const int wid = tid >> 6;
    const int row0 = blockIdx.x * 128;

    floatx4 acc[2][2];
    #pragma unroll
    for (int i = 0; i < 2; i++)
        #pragma unroll
        for (int j = 0; j < 2; j++)
            acc[i][j] = (floatx4){0.f, 0.f, 0.f, 0.f};

    int rrh[4], segh[4], grh[4];
    bool okh[4];
    #pragma unroll
    for (int h = 0; h < 4; h++) {
        int u = tid + h * 256;         // 0..1023
        rrh[h] = u >> 3;               // 0..127
        segh[h] = (u & 7) << 2;        // 0,4,..,28
        int gr = row0 + rrh[h];
        okh[h] = (gr < NROWS);
        grh[h] = okh[h] ? gr : 0;
    }

    shortx4 pf[4];
    #pragma unroll
    for (int h = 0; h < 4; h++) {
        shortx4 v = (shortx4){0, 0, 0, 0};
        if (okh[h]) v = *(const shortx4*)&xb[(size_t)grh[h] * DDIM + segh[h]];
        pf[h] = v;
    }

    for (int dt = 0; dt < 16; dt++) {
        __syncthreads();   // prior ds_reads complete before overwrite
        #pragma unroll
        for (int h = 0; h < 4; h++) {
            shortx4 sx = pf[h];
            shortx4 sq;
            #pragma unroll
            for (int e = 0; e < 4; e++) {
                float f = bf2f(sx[e]);
                sq[e] = (short)f2bf_rne(f * f);
            }
            *(shortx4*)&As_x[rrh[h] * LDG + segh[h]]  = sx;
            *(shortx4*)&As_sq[rrh[h] * LDG + segh[h]] = sq;
        }
        if (dt + 1 < 16) {
            #pragma unroll
            for (int h = 0; h < 4; h++) {
                shortx4 v = (shortx4){0, 0, 0, 0};
                if (okh[h])
                    v = *(const shortx4*)&xb[(size_t)grh[h] * DDIM +
                                             (dt + 1) * 32 + segh[h]];
                pf[h] = v;
            }
        }
        __syncthreads();

        short8 a_sq[2], a_x[2], b_sq[2], b_x[2];
        #pragma unroll
        for (int i = 0; i < 2; i++) {
            int off = (wid * 32 + i * 16 + lm) * LDG + lq * 8;
            a_sq[i] = *(const short8*)&As_sq[off];
            a_x[i]  = *(const short8*)&As_x[off];
        }
        #pragma unroll
        for (int j = 0; j < 2; j++) {
            const size_t bo = (size_t)(j * 16 + lm) * 1024 + dt * 32 + lq * 8;
            b_sq[j] = *(const short8*)&Bp[bo];
            b_x[j]  = *(const short8*)&Bp[bo + 512];
        }
        #pragma unroll
        for (int i = 0; i < 2; i++)
            #pragma unroll
            for (int j = 0; j < 2; j++) {
                acc[i][j] = __builtin_amdgcn_mfma_f32_16x16x32_bf16(
                    a_sq[i], b_sq[j], acc[i][j], 0, 0, 0);
                acc[i][j] = __builtin_amdgcn_mfma_f32_16x16x32_bf16(
                    a_x[i], b_x[j], acc[i][j], 0, 0, 0);
            }
    }

    float kst[2];
    kst[0] = konst[lm];
    kst[1] = konst[16 + lm];

    #pragma unroll
    for (int i = 0; i < 2; i++) {
        #pragma unroll
        for (int reg = 0; reg < 4; reg++) {
            int rr = row0 + wid * 32 + i * 16 + lq * 4 + reg;
            if (rr < NROWS) {
                out[(size_t)rr * KCL + lm]      = acc[i][0][reg] + kst[0];
                out[(size_t)rr * KCL + 16 + lm] = acc[i][1][reg] + kst[1];
            }
        }
    }
}

// ---------------------------------------------------------------------------
extern "C" void kernel_launch(void* const* d_in, const int* in_sizes, int n_in,
                              void* d_out, int out_size, void* d_ws, size_t ws_size,
                              hipStream_t stream)
{
    const float* x  = (const float*)d_in[0];
    const float* W1 = (const float*)d_in[1];
    const float* b1 = (const float*)d_in[2];
    const float* W2 = (const float*)d_in[3];
    const float* b2 = (const float*)d_in[4];
    const float* W3 = (const float*)d_in[5];
    const float* b3 = (const float*)d_in[6];
    float* out = (float*)d_out;              // [N*K] gmm_log, then [K*D] vars

    // ws layout (region extents unchanged):
    short* h1b     = (short*)d_ws;                       // [N][512] bf16 (h1)
    float* h2      = (float*)(h1b + (size_t)NROWS * H1DIM); // region: xb
    float* att     = h2 + (size_t)NROWS * H2DIM;         // region: attT+Patt
    float* P       = att + (size_t)NROWS * KCL;          // 196*32768 floats
    float* PattOld = P + (size_t)NCHUNK * 32768;         // unused (layout keep)
    float* S12     = PattOld + NCHUNK * KCL;
    float* att_sum = S12 + 2 * KCL * DDIM;
    short* Bp      = (short*)(att_sum + KCL);            // [32][1024] bf16
    float* konst   = (float*)(Bp + KCL * 1024);
    (void)ws_size; (void)in_sizes; (void)n_in; (void)out_size; (void)PattOld;

    // Overlays (stream-ordered, graph-safe):
    // xb (bf16 x) lives in the h2 region, written by gemm1_fused, alive to end.
    short* xb = (short*)h2;                  // [N][512] bf16
    // attT + PattN live in the att region.
    short* attT  = (short*)att;              // [32][NPAD] bf16 (6.4 MB)
    float* PattN = (float*)(attT + (size_t)KCL * NPAD);  // [NBLKL][32]
    // Weight bf16 transposes live at the head of P (dead until stats_mfma).
    short* W1T = (short*)P;                  // [512][512]
    short* W2T = W1T + H1DIM * DDIM;         // [256][512]
    short* W3T = W2T + H2DIM * H1DIM;        // [32][256]

    cvt_weights<<<dim3(1568), 256, 0, stream>>>(W1, W2, W3, W1T, W2T, W3T);

    int mblocks = (NROWS + 127) / 128;   // 782

    // h1 = softplus(x @ W1 + b1) bf16 + xb side-product. 128x512 tile.
    gemm1_fused<<<dim3(mblocks), 1024, 0, stream>>>(x, W1T, b1, h1b, xb);
    // fused h2-GEMM + logits + softmax -> attT (bf16) + PattN
    gemm2_logits<<<dim3(NBLKL), 512, 0, stream>>>(
        h1b, W2T, b2, W3T, b3, attT, PattN);
    stats_mfma<<<dim3(NCHUNK, 4), 256, 0, stream>>>(xb, attT, P);
    stats_reduce<<<dim3(128), 256, 0, stream>>>(P, PattN, S12, att_sum);
    finalize_stats<<<dim3(KCL), 256, 0, stream>>>(
        S12, att_sum, Bp, konst, out + (size_t)NROWS * KCL);
    gmm_out_mfma<<<dim3(mblocks), 256, 0, stream>>>(
        xb, Bp, konst, out);
}